// Round 14
// baseline (516.523 us; speedup 1.0000x reference)
//
#include <hip/hip_runtime.h>
#include <hip/hip_fp16.h>
#include <math.h>

static constexpr int NN = 100000;   // nodes
static constexpr int NE = 1600000;  // edges
static constexpr int NB_SCAN = (NN + 1023) / 1024;  // 98 scan blocks
static constexpr int NB_E = (NE + 255) / 256;       // 6250 edge blocks
static constexpr int N4 = NN * 128 / 4;             // 3.2M float4s in x
static constexpr int NB_CVT = (N4 + 255) / 256;     // 12500 cvt blocks

typedef __attribute__((ext_vector_type(8))) short bfvec8;  // 8 bf16 = 4 VGPRs
typedef __attribute__((ext_vector_type(4))) float fvec4;   // MFMA accumulator

// ---------------- bf16 helpers (fp32 <-> bf16 bit ops) ----------------
__device__ __forceinline__ float bflo(unsigned u) { return __uint_as_float(u << 16); }
__device__ __forceinline__ float bfhi(unsigned u) { return __uint_as_float(u & 0xFFFF0000u); }
__device__ __forceinline__ unsigned packbf2(float a, float b) {  // RTNE
  unsigned ua = __float_as_uint(a), ub = __float_as_uint(b);
  unsigned ra = (ua + 0x7fffu + ((ua >> 16) & 1u)) >> 16;
  unsigned rb = (ub + 0x7fffu + ((ub >> 16) & 1u)) >> 16;
  return ra | (rb << 16);
}
__device__ __forceinline__ unsigned short bf16r(float a) {  // RTNE single
  unsigned ua = __float_as_uint(a);
  return (unsigned short)((ua + 0x7fffu + ((ua >> 16) & 1u)) >> 16);
}
__device__ __forceinline__ float2 coefs(unsigned y) {  // {cB, cA} from packed half2
  return __half22float2(*(const __half2*)&y);
}

// ---------------- utility ----------------
__global__ __launch_bounds__(256) void k_zero(unsigned* __restrict__ p, int n) {
  int i = blockIdx.x * 256 + threadIdx.x;
  if (i < n) p[i] = 0u;
}

// Pack fp32 W[K][NC] into MFMA B-fragment-major bf16 (device body):
// Wf[(c*(K/32)+t)*64 + lane] = { W[t*32+(lane>>4)*8+j][c*16+(lane&15)], j=0..7 }
template <int K, int NC>
__device__ __forceinline__ void packWf_dev(const float* __restrict__ W,
                                           uint4* __restrict__ Wf, int i) {
  constexpr int TOT = (NC / 16) * (K / 32) * 64;
  if (i >= TOT) return;
  int lane = i & 63;
  int t = (i >> 6) % (K / 32);
  int c = i / ((K / 32) * 64);
  int col = c * 16 + (lane & 15);
  int k0 = t * 32 + (lane >> 4) * 8;
  float e[8];
  #pragma unroll
  for (int j = 0; j < 8; ++j) e[j] = W[(size_t)(k0 + j) * NC + col];
  Wf[i] = make_uint4(packbf2(e[0], e[1]), packbf2(e[2], e[3]),
                     packbf2(e[4], e[5]), packbf2(e[6], e[7]));
}

// ---------------- phase-1 fat kernel: deg+segrank | x->bf16 cvt | weight packs ----------------
// Segment rank: st edge -> prior st count (old>>16); ts edge -> prior ts count
// (old&0xFFFF)-(old>>16). Enables segment-sorted CSR rows (st-first, ts-second).
__global__ __launch_bounds__(256) void k_phase1(
    const int* __restrict__ dst, const int* __restrict__ rev,
    unsigned* __restrict__ cnt, unsigned short* __restrict__ rank16,
    const float4* __restrict__ X, uint2* __restrict__ Xb,
    const float* __restrict__ Wst, const float* __restrict__ Wts,
    const float* __restrict__ W1, const float* __restrict__ W2,
    const float* __restrict__ W3,
    uint4* __restrict__ WfS, uint4* __restrict__ WfT, uint4* __restrict__ Wf1,
    uint4* __restrict__ Wf2, uint4* __restrict__ Wf3) {
  int b = blockIdx.x;
  if (b < NB_E) {  // degree count + segment-rank capture
    int e = b * 256 + threadIdx.x;
    if (e < NE) {
      int r = rev[e];
      unsigned add = 1u + (r ? 0u : 0x10000u);
      unsigned old = atomicAdd(&cnt[dst[e]], add);
      unsigned rk = r ? (old & 0xFFFFu) - (old >> 16) : (old >> 16);
      rank16[e] = (unsigned short)rk;
    }
    return;
  }
  b -= NB_E;
  if (b < NB_CVT) {  // x fp32 -> bf16
    int i = b * 256 + threadIdx.x;
    if (i < N4) {
      float4 v = X[i];
      Xb[i] = make_uint2(packbf2(v.x, v.y), packbf2(v.z, v.w));
    }
    return;
  }
  b -= NB_CVT;
  if (b < 4)       packWf_dev<128, 64>(Wst, WfS, b * 256 + threadIdx.x);
  else if (b < 8)  packWf_dev<128, 64>(Wts, WfT, (b - 4) * 256 + threadIdx.x);
  else if (b < 12) packWf_dev<128, 64>(W1, Wf1, (b - 8) * 256 + threadIdx.x);
  else if (b < 24) packWf_dev<192, 128>(W2, Wf2, (b - 12) * 256 + threadIdx.x);
  else             packWf_dev<128, 16>(W3, Wf3, (b - 24) * 256 + threadIdx.x);
}

// ---------------- scan of (cnt & 0xFFFF) ----------------
__global__ __launch_bounds__(256) void k_scan1(const unsigned* __restrict__ cnt,
                                               unsigned* __restrict__ bsums) {
  int g = blockIdx.x, t = threadIdx.x;
  int base = g * 1024 + t * 4;
  unsigned s = 0;
  #pragma unroll
  for (int j = 0; j < 4; ++j) {
    int i = base + j;
    if (i < NN) s += cnt[i] & 0xFFFFu;
  }
  __shared__ unsigned sm[256];
  sm[t] = s;
  __syncthreads();
  for (int o = 128; o > 0; o >>= 1) {
    if (t < o) sm[t] += sm[t + o];
    __syncthreads();
  }
  if (t == 0) bsums[g] = sm[0];
}

__global__ __launch_bounds__(128) void k_scan2(unsigned* __restrict__ bsums) {
  __shared__ unsigned sm[128];
  int t = threadIdx.x;
  unsigned v = (t < NB_SCAN) ? bsums[t] : 0u;
  sm[t] = v;
  __syncthreads();
  for (int o = 1; o < 128; o <<= 1) {
    unsigned u = (t >= o) ? sm[t - o] : 0u;
    __syncthreads();
    sm[t] += u;
    __syncthreads();
  }
  if (t < NB_SCAN) bsums[t] = sm[t] - v;  // exclusive
}

__global__ __launch_bounds__(256) void k_scan3(const unsigned* __restrict__ cnt,
                                               const unsigned* __restrict__ bsums,
                                               unsigned* __restrict__ roff) {
  int g = blockIdx.x, t = threadIdx.x;
  int base = g * 1024 + t * 4;
  unsigned v[4];
  unsigned tsum = 0;
  #pragma unroll
  for (int j = 0; j < 4; ++j) {
    int i = base + j;
    v[j] = (i < NN) ? (cnt[i] & 0xFFFFu) : 0u;
    tsum += v[j];
  }
  __shared__ unsigned sm[256];
  sm[t] = tsum;
  __syncthreads();
  for (int o = 1; o < 256; o <<= 1) {
    unsigned u = (t >= o) ? sm[t - o] : 0u;
    __syncthreads();
    sm[t] += u;
    __syncthreads();
  }
  unsigned run = bsums[g] + sm[t] - tsum;  // exclusive prefix for this thread
  #pragma unroll
  for (int j = 0; j < 4; ++j) {
    int i = base + j;
    if (i < NN) {
      roff[i] = run;
      run += v[j];
      if (i == NN - 1) roff[NN] = run;
    }
  }
}

// dinv4[n] = {rsqrt(deg_st), rsqrt(deg_ts), rsqrt(deg_all), 0}
__global__ __launch_bounds__(256) void k_dinv(const unsigned* __restrict__ cnt,
                                              float4* __restrict__ dinv4) {
  int n = blockIdx.x * 256 + threadIdx.x;
  if (n >= NN) return;
  unsigned c = cnt[n];
  float all = (float)(c & 0xFFFFu) + 1.0f;
  float st = (float)(c >> 16) + 1.0f;
  float ts = all - st + 1.0f;
  dinv4[n] = make_float4(rsqrtf(st), rsqrtf(ts), rsqrtf(all), 0.0f);
}

// CSR fill, atomic-free + segment-sorted: st edges at roff[d]+rank,
// ts edges at roff[d]+stcnt+rank. ecsr[p] = {src, half2(cB, cA)} (no flag bit).
__global__ __launch_bounds__(256) void k_csr(const int* __restrict__ src,
                                             const int* __restrict__ dst,
                                             const int* __restrict__ rev,
                                             const unsigned short* __restrict__ rank16,
                                             const unsigned* __restrict__ roff,
                                             const unsigned* __restrict__ cnt,
                                             const float4* __restrict__ dinv4,
                                             uint2* __restrict__ ecsr) {
  int e = blockIdx.x * 256 + threadIdx.x;
  if (e >= NE) return;
  int s = src[e], d = dst[e];
  int r = rev[e];
  float4 sv = dinv4[s];
  float4 dv = dinv4[d];
  float cB = r ? (sv.y * dv.y) : (sv.x * dv.x);
  float cA = sv.z * dv.z;
  __half2 h = __floats2half2_rn(cB, cA);
  unsigned stc = cnt[d] >> 16;
  unsigned p = roff[d] + (r ? stc + rank16[e] : (unsigned)rank16[e]);
  ecsr[p] = make_uint2((unsigned)s, *(const unsigned*)&h);
}

// ---------------- layer-1 edge aggregation over x (bf16 [N,128]) ----------------
// One wave per node; lane holds cols {2*lane, 2*lane+1}.
// Segment-sorted rows: st sub-loop then ts sub-loop, each 4 FMA/edge, branch-free.
// 32-bit gather indices (no flag mask).
__global__ __launch_bounds__(256) void k_agg0(const unsigned* __restrict__ roff,
                                              const unsigned* __restrict__ cnt,
                                              const uint2* __restrict__ E,
                                              const float4* __restrict__ dinv4,
                                              const unsigned* __restrict__ Xb,
                                              unsigned* __restrict__ aST,
                                              unsigned* __restrict__ aTS,
                                              unsigned* __restrict__ aAL) {
  int wid = threadIdx.x >> 6;
  int lane = threadIdx.x & 63;
  int d = blockIdx.x * 4 + wid;
  if (d >= NN) return;
  unsigned ro = roff[d], re = roff[d + 1];
  unsigned mid = ro + (cnt[d] >> 16);
  float s0l = 0.f, s0h = 0.f, s1l = 0.f, s1h = 0.f, s2l = 0.f, s2h = 0.f;
  unsigned i = ro;
#define A0_EDGE(e, u, SL, SH)                                      \
  {                                                                \
    float2 c = coefs(e.y);                                         \
    float xl = bflo(u), xh = bfhi(u);                              \
    s2l = fmaf(c.y, xl, s2l); s2h = fmaf(c.y, xh, s2h);            \
    SL = fmaf(c.x, xl, SL); SH = fmaf(c.x, xh, SH);                \
  }
  // st segment -> s0
  for (; i + 4 <= mid; i += 4) {
    uint2 e0 = E[i], e1 = E[i + 1], e2 = E[i + 2], e3 = E[i + 3];
    unsigned u0 = Xb[e0.x * 64u + lane];
    unsigned u1 = Xb[e1.x * 64u + lane];
    unsigned u2 = Xb[e2.x * 64u + lane];
    unsigned u3 = Xb[e3.x * 64u + lane];
    A0_EDGE(e0, u0, s0l, s0h) A0_EDGE(e1, u1, s0l, s0h)
    A0_EDGE(e2, u2, s0l, s0h) A0_EDGE(e3, u3, s0l, s0h)
  }
  for (; i < mid; ++i) {
    uint2 e = E[i];
    unsigned u = Xb[e.x * 64u + lane];
    A0_EDGE(e, u, s0l, s0h)
  }
  // ts segment -> s1
  for (; i + 4 <= re; i += 4) {
    uint2 e0 = E[i], e1 = E[i + 1], e2 = E[i + 2], e3 = E[i + 3];
    unsigned u0 = Xb[e0.x * 64u + lane];
    unsigned u1 = Xb[e1.x * 64u + lane];
    unsigned u2 = Xb[e2.x * 64u + lane];
    unsigned u3 = Xb[e3.x * 64u + lane];
    A0_EDGE(e0, u0, s1l, s1h) A0_EDGE(e1, u1, s1l, s1h)
    A0_EDGE(e2, u2, s1l, s1h) A0_EDGE(e3, u3, s1l, s1h)
  }
  for (; i < re; ++i) {
    uint2 e = E[i];
    unsigned u = Xb[e.x * 64u + lane];
    A0_EDGE(e, u, s1l, s1h)
  }
#undef A0_EDGE
  // self-loop terms: dinv^2 * x_d per mask
  float4 dv = dinv4[d];
  unsigned u = Xb[(unsigned)d * 64u + lane];
  float xl = bflo(u), xh = bfhi(u);
  float rs = dv.x * dv.x, rt = dv.y * dv.y, ra = dv.z * dv.z;
  s0l = fmaf(rs, xl, s0l); s0h = fmaf(rs, xh, s0h);
  s1l = fmaf(rt, xl, s1l); s1h = fmaf(rt, xh, s1h);
  s2l = fmaf(ra, xl, s2l); s2h = fmaf(ra, xh, s2h);
  aST[(size_t)d * 64 + lane] = packbf2(s0l, s0h);
  aTS[(size_t)d * 64 + lane] = packbf2(s1l, s1h);
  aAL[(size_t)d * 64 + lane] = packbf2(s2l, s2h);
}

// ---------------- fused layer-1 GEMM: h1 = relu([aST@Wst | aTS@Wts | aAL@W1] + b) ----------------
// h1 bf16 [N,192], layout [st|ts|all] (matches W2 row order).
__global__ __launch_bounds__(256) void k_mgemm1f(const unsigned short* __restrict__ A0,
                                                 const unsigned short* __restrict__ A1,
                                                 const unsigned short* __restrict__ A2,
                                                 const bfvec8* __restrict__ W0,
                                                 const bfvec8* __restrict__ W1f,
                                                 const bfvec8* __restrict__ W2f,
                                                 const float* __restrict__ b0,
                                                 const float* __restrict__ b1p,
                                                 const float* __restrict__ b2p,
                                                 unsigned short* __restrict__ O) {
  int wid = threadIdx.x >> 6, lane = threadIdx.x & 63;
  int rt = blockIdx.x * 4 + wid;
  if (rt >= NN / 16) return;
  int r0 = rt * 16, row = lane & 15, hi = lane >> 4;
  #pragma unroll
  for (int b = 0; b < 3; ++b) {
    const unsigned short* Ab = (b == 0 ? A0 : b == 1 ? A1 : A2) + (size_t)(r0 + row) * 128 + hi * 8;
    const bfvec8* Wb = (b == 0 ? W0 : b == 1 ? W1f : W2f);
    const float* bb = (b == 0 ? b0 : b == 1 ? b1p : b2p);
    bfvec8 af[4];
    #pragma unroll
    for (int t = 0; t < 4; ++t) af[t] = *(const bfvec8*)(Ab + t * 32);
    #pragma unroll
    for (int ct = 0; ct < 4; ++ct) {
      fvec4 acc = {0.f, 0.f, 0.f, 0.f};
      #pragma unroll
      for (int t = 0; t < 4; ++t)
        acc = __builtin_amdgcn_mfma_f32_16x16x32_bf16(af[t], Wb[(ct * 4 + t) * 64 + lane],
                                                      acc, 0, 0, 0);
      float bv = bb[ct * 16 + row];
      #pragma unroll
      for (int r = 0; r < 4; ++r)
        O[(size_t)(r0 + hi * 4 + r) * 192 + b * 64 + ct * 16 + row] =
            bf16r(fmaxf(acc[r] + bv, 0.f));
    }
  }
}

// ---------------- MFMA GEMM: O[N,NC] = A[N,K](bf16) @ Wf(bf16 frags) ----------------
// OM: 0 = fp32 out [N,NC]; 1 = bf16 out [N,NC].
template <int K, int NC, int OM>
__global__ __launch_bounds__(256) void k_mgemm(const unsigned short* __restrict__ A,
                                               const bfvec8* __restrict__ Wf,
                                               void* __restrict__ Op) {
  constexpr int KS = K / 32, NCT = NC / 16;
  int wid = threadIdx.x >> 6, lane = threadIdx.x & 63;
  int rt = blockIdx.x * 4 + wid;
  if (rt >= NN / 16) return;
  int r0 = rt * 16;
  int row = lane & 15, hi = lane >> 4;
  bfvec8 af[KS];
  const unsigned short* Ab = A + (size_t)(r0 + row) * K + hi * 8;
  #pragma unroll
  for (int t = 0; t < KS; ++t) af[t] = *(const bfvec8*)(Ab + t * 32);
  #pragma unroll
  for (int c = 0; c < NCT; ++c) {
    fvec4 acc = {0.f, 0.f, 0.f, 0.f};
    #pragma unroll
    for (int t = 0; t < KS; ++t)
      acc = __builtin_amdgcn_mfma_f32_16x16x32_bf16(af[t], Wf[(c * KS + t) * 64 + lane],
                                                    acc, 0, 0, 0);
    if constexpr (OM == 0) {
      float* O = (float*)Op;
      #pragma unroll
      for (int r = 0; r < 4; ++r)
        O[(size_t)(r0 + hi * 4 + r) * NC + c * 16 + row] = acc[r];
    } else {
      unsigned short* O = (unsigned short*)Op;
      #pragma unroll
      for (int r = 0; r < 4; ++r)
        O[(size_t)(r0 + hi * 4 + r) * NC + c * 16 + row] = bf16r(acc[r]);
    }
  }
}

// ---------------- layer-2 aggregation: T2' bf16 [N,128], unroll x4 ----------------
__global__ __launch_bounds__(256) void k_agg2(const unsigned* __restrict__ roff,
                                              const uint2* __restrict__ E,
                                              const float4* __restrict__ dinv4,
                                              const unsigned* __restrict__ Tb,
                                              const float* __restrict__ b2,
                                              unsigned* __restrict__ h2) {
  int wid = threadIdx.x >> 6;
  int lane = threadIdx.x & 63;
  int d = blockIdx.x * 4 + wid;
  if (d >= NN) return;
  unsigned ro = roff[d], re = roff[d + 1];
  float sl = 0.f, sh = 0.f;
  unsigned i = ro;
#define A2_EDGE(e, u)                                   \
  {                                                     \
    float cA = __high2float(*(const __half2*)&e.y);     \
    sl = fmaf(cA, bflo(u), sl);                         \
    sh = fmaf(cA, bfhi(u), sh);                         \
  }
  for (; i + 4 <= re; i += 4) {
    uint2 e0 = E[i], e1 = E[i + 1], e2 = E[i + 2], e3 = E[i + 3];
    unsigned u0 = Tb[e0.x * 64u + lane];
    unsigned u1 = Tb[e1.x * 64u + lane];
    unsigned u2 = Tb[e2.x * 64u + lane];
    unsigned u3 = Tb[e3.x * 64u + lane];
    A2_EDGE(e0, u0) A2_EDGE(e1, u1) A2_EDGE(e2, u2) A2_EDGE(e3, u3)
  }
  for (; i < re; ++i) {
    uint2 e = E[i];
    unsigned u = Tb[e.x * 64u + lane];
    A2_EDGE(e, u)
  }
#undef A2_EDGE
  float dz = dinv4[d].z;
  float ra = dz * dz;
  unsigned u = Tb[(unsigned)d * 64u + lane];
  sl = fmaf(ra, bflo(u), sl); sh = fmaf(ra, bfhi(u), sh);
  float2 bb = ((const float2*)b2)[lane];
  sl += bb.x; sh += bb.y;
  h2[(size_t)d * 64 + lane] = packbf2(sl, sh);
}

// ---------------- layer-3 aggregation + log_softmax: T3 fp32 [N,16], unroll x4 ----------------
__global__ __launch_bounds__(256) void k_agg3(const unsigned* __restrict__ roff,
                                              const uint2* __restrict__ E,
                                              const float4* __restrict__ dinv4,
                                              const float* __restrict__ T,
                                              const float* __restrict__ b3,
                                              float* __restrict__ out) {
  int g = threadIdx.x >> 4;
  int l = threadIdx.x & 15;
  int d = blockIdx.x * 16 + g;
  if (d >= NN) return;
  unsigned ro = roff[d], re = roff[d + 1];
  float a = 0.f;
  unsigned i = ro;
  for (; i + 4 <= re; i += 4) {
    uint2 e0 = E[i], e1 = E[i + 1], e2 = E[i + 2], e3 = E[i + 3];
    float t0 = T[e0.x * 16u + l];
    float t1 = T[e1.x * 16u + l];
    float t2 = T[e2.x * 16u + l];
    float t3 = T[e3.x * 16u + l];
    a = fmaf(__high2float(*(const __half2*)&e0.y), t0, a);
    a = fmaf(__high2float(*(const __half2*)&e1.y), t1, a);
    a = fmaf(__high2float(*(const __half2*)&e2.y), t2, a);
    a = fmaf(__high2float(*(const __half2*)&e3.y), t3, a);
  }
  for (; i < re; ++i) {
    uint2 e = E[i];
    a = fmaf(__high2float(*(const __half2*)&e.y), T[e.x * 16u + l], a);
  }
  float dz = dinv4[d].z;
  a = fmaf(dz * dz, T[(unsigned)d * 16u + l], a) + b3[l];
  float m = a;
  #pragma unroll
  for (int o = 8; o > 0; o >>= 1) m = fmaxf(m, __shfl_xor(m, o, 16));
  float ex = expf(a - m);
  float sm = ex;
  #pragma unroll
  for (int o = 8; o > 0; o >>= 1) sm += __shfl_xor(sm, o, 16);
  out[(size_t)d * 16 + l] = a - m - logf(sm);
}

// ---------------- host-side launch ----------------
extern "C" void kernel_launch(void* const* d_in, const int* in_sizes, int n_in,
                              void* d_out, int out_size, void* d_ws, size_t ws_size,
                              hipStream_t stream) {
  const float* x   = (const float*)d_in[0];
  const int* ei    = (const int*)d_in[1];
  const int* srcp  = ei;
  const int* dstp  = ei + NE;
  const int* revp  = (const int*)d_in[2];
  const float* Wst = (const float*)d_in[3];
  const float* bst = (const float*)d_in[4];
  const float* Wts = (const float*)d_in[5];
  const float* bts = (const float*)d_in[6];
  const float* W1  = (const float*)d_in[7];
  const float* b1  = (const float*)d_in[8];
  const float* W2  = (const float*)d_in[9];
  const float* b2  = (const float*)d_in[10];
  const float* W3  = (const float*)d_in[11];
  const float* b3  = (const float*)d_in[12];
  float* out = (float*)d_out;

  char* ws = (char*)d_ws;
  size_t off = 0;
  auto alloc = [&](size_t bytes) -> void* {
    off = (off + 255) & ~size_t(255);
    void* p = ws + off;
    off += bytes;
    return p;
  };
  unsigned* cnt    = (unsigned*)alloc(sizeof(unsigned) * NN);
  unsigned* roff   = (unsigned*)alloc(sizeof(unsigned) * (NN + 1));
  unsigned* bsums  = (unsigned*)alloc(sizeof(unsigned) * 128);
  unsigned short* rank16 = (unsigned short*)alloc(sizeof(unsigned short) * NE);  // 3.2 MB
  float4*   dinv4  = (float4*)alloc(sizeof(float4) * NN);
  uint2*    ecsr   = (uint2*)alloc(sizeof(uint2) * NE);  // 12.8 MB
  // bufX: 25.6 MB (aggST bf16 [N,128]; later T2' bf16 [N,128] and T3 fp32 [N,16])
  char*     bufX   = (char*)alloc((size_t)NN * 128 * 2);
  unsigned* aggTS  = (unsigned*)alloc(sizeof(unsigned) * (size_t)NN * 64);  // 25.6 MB
  unsigned* aggAL  = (unsigned*)alloc(sizeof(unsigned) * (size_t)NN * 64);  // 25.6 MB
  // bufY: 38.4 MB (h1 bf16 [N,192]; later h2 bf16 [N,128])
  char*     bufY   = (char*)alloc((size_t)NN * 192 * 2);
  // xb: 25.6 MB (x in bf16 row-major [N,128])
  unsigned short* xb = (unsigned short*)alloc((size_t)NN * 128 * 2);
  uint4*    WfS    = (uint4*)alloc(sizeof(uint4) * 4 * 4 * 64);
  uint4*    WfT    = (uint4*)alloc(sizeof(uint4) * 4 * 4 * 64);
  uint4*    Wf1    = (uint4*)alloc(sizeof(uint4) * 4 * 4 * 64);
  uint4*    Wf2    = (uint4*)alloc(sizeof(uint4) * 8 * 6 * 64);
  uint4*    Wf3    = (uint4*)alloc(sizeof(uint4) * 1 * 4 * 64);
  (void)ws_size; (void)in_sizes; (void)n_in; (void)out_size;

  const int nbN = (NN + 255) / 256;
  const int nbM = (NN / 16 + 3) / 4;  // MFMA gemm blocks (4 waves x 16-row tiles)
  const int nbP1 = NB_E + NB_CVT + 25;  // fat phase-1 grid

  // Phase 0: zero degree counters
  hipLaunchKernelGGL(k_zero, dim3(nbN), dim3(256), 0, stream, cnt, NN);
  // Phase 1 (fat): deg+segrank | x->bf16 | weight packs
  hipLaunchKernelGGL(k_phase1, dim3(nbP1), dim3(256), 0, stream,
                     dstp, revp, cnt, rank16, (const float4*)x, (uint2*)xb,
                     Wst, Wts, W1, W2, W3, WfS, WfT, Wf1, Wf2, Wf3);
  // Scan + dinv
  hipLaunchKernelGGL(k_scan1, dim3(NB_SCAN), dim3(256), 0, stream, cnt, bsums);
  hipLaunchKernelGGL(k_scan2, dim3(1), dim3(128), 0, stream, bsums);
  hipLaunchKernelGGL(k_scan3, dim3(NB_SCAN), dim3(256), 0, stream, cnt, bsums, roff);
  hipLaunchKernelGGL(k_dinv, dim3(nbN), dim3(256), 0, stream, cnt, dinv4);
  // CSR fill (atomic-free, segment-sorted)
  hipLaunchKernelGGL(k_csr, dim3(NB_E), dim3(256), 0, stream,
                     srcp, dstp, revp, rank16, roff, cnt, dinv4, ecsr);

  // Layer 1: aggregate x under 3 masks, then fused block GEMM + bias + relu
  hipLaunchKernelGGL(k_agg0, dim3(NN / 4), dim3(256), 0, stream,
                     roff, cnt, ecsr, dinv4, (const unsigned*)xb,
                     (unsigned*)bufX, aggTS, aggAL);
  hipLaunchKernelGGL(k_mgemm1f, dim3(nbM), dim3(256), 0, stream,
                     (const unsigned short*)bufX, (const unsigned short*)aggTS,
                     (const unsigned short*)aggAL,
                     (const bfvec8*)WfS, (const bfvec8*)WfT, (const bfvec8*)Wf1,
                     bst, bts, b1, (unsigned short*)bufY);

  // Layer 2: T2' = h1 @ Wf2 -> bufX (bf16 [N,128]); agg -> bufY (h2 bf16 [N,128])
  hipLaunchKernelGGL((k_mgemm<192, 128, 1>), dim3(nbM), dim3(256), 0, stream,
                     (const unsigned short*)bufY, (const bfvec8*)Wf2, bufX);
  hipLaunchKernelGGL(k_agg2, dim3(NN / 4), dim3(256), 0, stream,
                     roff, ecsr, dinv4, (const unsigned*)bufX, b2, (unsigned*)bufY);

  // Layer 3: T3 = h2 @ Wf3 -> bufX fp32 [N,16]; agg + log_softmax -> out
  hipLaunchKernelGGL((k_mgemm<128, 16, 0>), dim3(nbM), dim3(256), 0, stream,
                     (const unsigned short*)bufY, (const bfvec8*)Wf3, bufX);
  hipLaunchKernelGGL(k_agg3, dim3(NN / 16), dim3(256), 0, stream,
                     roff, ecsr, dinv4, (const float*)bufX, b3, out);
}